// Round 8
// baseline (297.564 us; speedup 1.0000x reference)
//
#include <hip/hip_runtime.h>
#include <hip/hip_bf16.h>
#include <stdint.h>

typedef float f32x4 __attribute__((ext_vector_type(4)));
typedef __bf16 bf16x8 __attribute__((ext_vector_type(8)));
typedef unsigned short ushort8 __attribute__((ext_vector_type(8)));

#define NB 8
#define NS 8192
#define ND 512
#define NM (NB * NS)      // 65536 rows
#define NK 512            // reduction dim

// ---------------- f32 -> bf16 (RNE) ----------------
__device__ __forceinline__ unsigned short f2bf(float f) {
  unsigned u = __float_as_uint(f);
  u += 0x7FFFu + ((u >> 16) & 1u);
  return (unsigned short)(u >> 16);
}

__global__ __launch_bounds__(256) void cvt_bf16(const float* __restrict__ src,
                                                unsigned short* __restrict__ dst,
                                                int n8) {
  int i = blockIdx.x * 256 + threadIdx.x;
  if (i >= n8) return;
  const float4* s = reinterpret_cast<const float4*>(src + (size_t)i * 8);
  float4 v0 = s[0], v1 = s[1];
  ushort8 o;
  o[0] = f2bf(v0.x); o[1] = f2bf(v0.y); o[2] = f2bf(v0.z); o[3] = f2bf(v0.w);
  o[4] = f2bf(v1.x); o[5] = f2bf(v1.y); o[6] = f2bf(v1.z); o[7] = f2bf(v1.w);
  *reinterpret_cast<ushort8*>(dst + (size_t)i * 8) = o;
}

// ---------------- 256x256 2-phase bf16 GEMM + a/b epilogue + chunk aggregates ----
// Block: 256 seq rows x (128 hidden + matching 128 gate cols). 8 waves (2M x 4N),
// BK=64, double-buffered LDS (2 x 64KB). Per K-tile: issue next-tile
// global_load_lds FIRST, then 24 ds_read + 64 MFMA per wave (~600 cyc compute
// phase covers load latency), then ONE __syncthreads(). T2 XOR swizzle via
// pre-swizzled global source; T1 bijective XCD grid swizzle.
// Epilogue: packed (a|b) bf16 store + per-128-row-chunk affine aggregates
// (each wm-half is exactly one scan chunk -> no cross-wave combine).
__global__ __launch_bounds__(512, 1) void gemm_ab(const unsigned short* __restrict__ xb,
                                                  const unsigned short* __restrict__ wb,
                                                  uint32_t* __restrict__ pk,
                                                  float* __restrict__ aggA,
                                                  float* __restrict__ aggB) {
  __shared__ __align__(16) unsigned short lds[65536];  // 128 KB
  float* gbuf = reinterpret_cast<float*>(lds);         // 256x128 f32 alias (epilogue)

  const int tid = threadIdx.x;
  const int w = tid >> 6;          // wave 0..7
  const int lane = tid & 63;
  const int wm = w >> 2;           // 0..1 : 128-row half
  const int wn = w & 3;            // 0..3 : 64-col quarter (0,1 hidden / 2,3 gate)
  const int fr = lane & 15;
  const int kg = lane >> 4;        // 0..3

  // T1 bijective XCD swizzle: 1024 blocks = 256 mblk x 4 nblk
  const int orig = blockIdx.x;
  const int wg = (orig & 7) * 128 + (orig >> 3);
  const int mblk = wg >> 2;
  const int nblk = wg & 3;
  const int m0 = mblk * 256;
  const int n0 = nblk * 128;       // channel base (128 channels/block)

  const int srow = lane >> 3;                     // 0..7
  const int scol = (((lane & 7) ^ srow) * 8);     // pre-swizzled source col (bf16)

  // stage one K-tile: A 32KB + B 32KB, dest linear (wave-uniform base + lane*16B)
  auto stage = [&](int buf, int kt) {
    const int k0 = kt << 6;
    unsigned short* baseA = lds + buf * 32768;
    unsigned short* baseB = lds + buf * 32768 + 16384;
#pragma unroll
    for (int hh = 0; hh < 4; ++hh) {
      int rowb = hh * 64 + w * 8;                 // wave-uniform
      int row = rowb + srow;
      const unsigned short* srcA = xb + (size_t)(m0 + row) * NK + k0 + scol;
      __builtin_amdgcn_global_load_lds(
          (const __attribute__((address_space(1))) void*)srcA,
          (__attribute__((address_space(3))) void*)(baseA + rowb * 64),
          16, 0, 0);
      int e = (row < 128) ? (n0 + row) : (384 + n0 + row);  // hidden | gate W-rows
      const unsigned short* srcB = wb + (size_t)e * NK + k0 + scol;
      __builtin_amdgcn_global_load_lds(
          (const __attribute__((address_space(1))) void*)srcB,
          (__attribute__((address_space(3))) void*)(baseB + rowb * 64),
          16, 0, 0);
    }
  };

  f32x4 acc[8][4];
#pragma unroll
  for (int i = 0; i < 8; ++i)
#pragma unroll
    for (int j = 0; j < 4; ++j) acc[i][j] = (f32x4)0.0f;

  // prologue
  stage(0, 0);
  __syncthreads();

#pragma unroll 1
  for (int kt = 0; kt < 8; ++kt) {
    const int cur = kt & 1;
    if (kt < 7) stage(cur ^ 1, kt + 1);           // issue next-tile loads FIRST

    const char* ldsA = (const char*)(lds + cur * 32768);
    const char* ldsB = ldsA + 32768;
#pragma unroll
    for (int kk = 0; kk < 64; kk += 32) {
      bf16x8 af[8], bfr[4];
#pragma unroll
      for (int m = 0; m < 8; ++m) {
        int rowA = (wm << 7) + (m << 4) + fr;
        int swz = (kk * 2 + kg * 16) ^ ((rowA & 7) << 4);
        af[m] = *reinterpret_cast<const bf16x8*>(ldsA + rowA * 128 + swz);
      }
#pragma unroll
      for (int n = 0; n < 4; ++n) {
        int rowB = (wn << 6) + (n << 4) + fr;
        int swz = (kk * 2 + kg * 16) ^ ((rowB & 7) << 4);
        bfr[n] = *reinterpret_cast<const bf16x8*>(ldsB + rowB * 128 + swz);
      }
#pragma unroll
      for (int m = 0; m < 8; ++m)
#pragma unroll
        for (int n = 0; n < 4; ++n)
          acc[m][n] = __builtin_amdgcn_mfma_f32_16x16x32_bf16(af[m], bfr[n], acc[m][n], 0, 0, 0);
    }
    __syncthreads();   // one barrier per K-tile
  }

  // ---------------- epilogue ----------------
  // gate waves (wn>=2) publish gate values via swizzled gbuf.
  if (wn >= 2) {
    const int cb = (wn - 2) << 6;
#pragma unroll
    for (int mi = 0; mi < 8; ++mi)
#pragma unroll
      for (int ni = 0; ni < 4; ++ni)
#pragma unroll
        for (int r = 0; r < 4; ++r) {
          int row = (wm << 7) + (mi << 4) + (kg << 2) + r;
          int ch = cb + (ni << 4) + fr;
          gbuf[(row << 7) + (ch ^ (((row >> 2) & 3) << 4))] = acc[mi][ni][r];
        }
  }
  __syncthreads();
  // hidden waves: fuse a,b; store packed (a|b<<16); build 128-row chunk aggregate.
  if (wn < 2) {
    const int cb = wn << 6;
    float A128[4], B128[4];
#pragma unroll
    for (int ni = 0; ni < 4; ++ni) {
      float Ami[8], Bmi[8];
#pragma unroll
      for (int mi = 0; mi < 8; ++mi) {
        float As = 1.0f, Bs = 0.0f;
#pragma unroll
        for (int r = 0; r < 4; ++r) {
          int row = (wm << 7) + (mi << 4) + (kg << 2) + r;
          int ch = cb + (ni << 4) + fr;
          float hid = acc[mi][ni][r];
          float gat = gbuf[(row << 7) + (ch ^ (((row >> 2) & 3) << 4))];
          float a = 1.0f / (1.0f + __expf(gat));     // sigmoid(-gate)
          float z = 1.0f - a;                        // sigmoid(gate)
          float g = (hid >= 0.0f) ? (hid + 0.5f) : (1.0f / (1.0f + __expf(-hid)));
          float bb = z * g;
          pk[(size_t)(m0 + row) * ND + n0 + ch] =
              ((uint32_t)f2bf(bb) << 16) | (uint32_t)f2bf(a);
          Bs = fmaf(a, Bs, bb);   // ordered: r ascending
          As *= a;
        }
        Ami[mi] = As; Bmi[mi] = Bs;
      }
      // ordered affine composition across kg (rows kg*4..kg*4+3 within 16-row group)
#pragma unroll
      for (int mi = 0; mi < 8; ++mi) {
        float pA = __shfl_xor(Ami[mi], 16);
        float pB = __shfl_xor(Bmi[mi], 16);
        Bmi[mi] = (kg & 1) ? fmaf(Ami[mi], pB, Bmi[mi]) : fmaf(pA, Bmi[mi], pB);
        Ami[mi] *= pA;
        pA = __shfl_xor(Ami[mi], 32);
        pB = __shfl_xor(Bmi[mi], 32);
        Bmi[mi] = (kg & 2) ? fmaf(Ami[mi], pB, Bmi[mi]) : fmaf(pA, Bmi[mi], pB);
        Ami[mi] *= pA;
      }
      // serial over the 8 16-row groups (ascending)
      float As = Ami[0], Bs = Bmi[0];
#pragma unroll
      for (int mi = 1; mi < 8; ++mi) { Bs = fmaf(Ami[mi], Bs, Bmi[mi]); As *= Ami[mi]; }
      A128[ni] = As; B128[ni] = Bs;
    }
    if (kg == 0) {
      // this wm-half IS scan chunk (mblk*2 + wm)
#pragma unroll
      for (int ni = 0; ni < 4; ++ni) {
        int ch = cb + (ni << 4) + fr;
        size_t o = (size_t)(mblk * 2 + wm) * ND + n0 + ch;
        aggA[o] = A128[ni];
        aggB[o] = B128[ni];
      }
    }
  }
}

// ---------------- scan pass2: prefix + rescan, write out f32 ----------------
__global__ __launch_bounds__(256) void scan_pass2(const uint32_t* __restrict__ pk,
                                                  const float* __restrict__ aggA,
                                                  const float* __restrict__ aggB,
                                                  float* __restrict__ out,
                                                  float* __restrict__ nextp) {
  int bid = blockIdx.x;
  int b = bid >> 6;
  int c = bid & 63;
  int d2 = threadIdx.x;        // channel-pair 0..255

  float h0 = 0.0f, h1 = 0.0f;
  for (int cc = 0; cc < c; ++cc) {
    int o = (b * 64 + cc) * ND + d2 * 2;
    float2 Aa = *reinterpret_cast<const float2*>(&aggA[o]);
    float2 Bb = *reinterpret_cast<const float2*>(&aggB[o]);
    h0 = fmaf(Aa.x, h0, Bb.x);
    h1 = fmaf(Aa.y, h1, Bb.y);
  }
  size_t base = (size_t)(b * NS + c * 128) * ND + d2 * 2;
#pragma unroll 4
  for (int t = 0; t < 128; ++t) {
    size_t idx = base + (size_t)t * ND;
    uint2 v = *reinterpret_cast<const uint2*>(pk + idx);
    float a0 = __uint_as_float(v.x << 16);
    float b0 = __uint_as_float(v.x & 0xffff0000u);
    float a1 = __uint_as_float(v.y << 16);
    float b1 = __uint_as_float(v.y & 0xffff0000u);
    h0 = fmaf(a0, h0, b0);
    h1 = fmaf(a1, h1, b1);
    *reinterpret_cast<float2*>(&out[idx]) = make_float2(h0, h1);
  }
  if (c == 63) {
    *reinterpret_cast<float2*>(&nextp[b * ND + d2 * 2]) = make_float2(h0, h1);
  }
}

// ---------------- launcher ----------------
extern "C" void kernel_launch(void* const* d_in, const int* in_sizes, int n_in,
                              void* d_out, int out_size, void* d_ws, size_t ws_size,
                              hipStream_t stream) {
  const float* x = (const float*)d_in[0];   // (8, 8192, 512) f32
  const float* W = (const float*)d_in[1];   // (1024, 512) f32
  float* out = (float*)d_out;               // 33554432 + 4096 f32

  char* ws = (char*)d_ws;
  unsigned short* xb  = (unsigned short*)ws;                              // 64 MB
  unsigned short* wbf = (unsigned short*)(ws + (size_t)64 * 1024 * 1024); // 1 MB
  uint32_t* pk = (uint32_t*)(ws + (size_t)65 * 1024 * 1024);              // 128 MB
  float* aggA = (float*)(ws + (size_t)193 * 1024 * 1024);                 // 1 MB
  float* aggB = (float*)(ws + (size_t)194 * 1024 * 1024);                 // 1 MB
  float* nextp = out + (size_t)NM * ND;

  cvt_bf16<<<16384, 256, 0, stream>>>(x, xb, (NM * NK) / 8);
  cvt_bf16<<<256, 256, 0, stream>>>(W, wbf, (1024 * NK) / 8);
  gemm_ab<<<1024, 512, 0, stream>>>(xb, wbf, pk, aggA, aggB);
  scan_pass2<<<512, 256, 0, stream>>>(pk, aggA, aggB, out, nextp);
}

// Round 11
// 231.361 us; speedup vs baseline: 1.2861x; 1.2861x over previous
//
#include <hip/hip_runtime.h>
#include <hip/hip_bf16.h>
#include <stdint.h>

typedef float f32x4 __attribute__((ext_vector_type(4)));
typedef __bf16 bf16x8 __attribute__((ext_vector_type(8)));
typedef unsigned short ushort8 __attribute__((ext_vector_type(8)));

#define NB 8
#define NS 8192
#define ND 512
#define NM (NB * NS)      // 65536 rows
#define NK 512            // reduction dim

// ---------------- f32 -> bf16 (RNE) ----------------
__device__ __forceinline__ unsigned short f2bf(float f) {
  unsigned u = __float_as_uint(f);
  u += 0x7FFFu + ((u >> 16) & 1u);
  return (unsigned short)(u >> 16);
}

__global__ __launch_bounds__(256) void cvt_bf16(const float* __restrict__ src,
                                                unsigned short* __restrict__ dst,
                                                int n8) {
  int i = blockIdx.x * 256 + threadIdx.x;
  if (i >= n8) return;
  const float4* s = reinterpret_cast<const float4*>(src + (size_t)i * 8);
  float4 v0 = s[0], v1 = s[1];
  ushort8 o;
  o[0] = f2bf(v0.x); o[1] = f2bf(v0.y); o[2] = f2bf(v0.z); o[3] = f2bf(v0.w);
  o[4] = f2bf(v1.x); o[5] = f2bf(v1.y); o[6] = f2bf(v1.z); o[7] = f2bf(v1.w);
  *reinterpret_cast<ushort8*>(dst + (size_t)i * 8) = o;
}

// ---------------- 128x128 2-phase bf16 GEMM, in-register a/b epilogue ----------
// Block: 128 seq rows (= one scan chunk) x 64 channels (128 W-rows: 64 hidden +
// 64 gate). 4 waves; wave (wr,wc) computes A-rows [64wr,64wr+64) x B-frags that
// MIX hidden and gate: frag n<2 -> hidden W-rows 32wc+16n, frag n>=2 -> gate
// W-rows 64+32wc+16(n-2). So hid=acc[m][n], gat=acc[m][n+2] live in the SAME
// thread -> epilogue is pure-register (no LDS gate exchange, all waves work).
// K-loop = R6's measured-best 2-phase dbuf (stage-first, one __syncthreads).
// Epilogue also emits per-chunk scan aggregates (ordered kg-shuffles + tiny
// cross-wr LDS combine) and packed (a|b) bf16 pk words.
__global__ __launch_bounds__(256) void gemm_ab(const unsigned short* __restrict__ xb,
                                               const unsigned short* __restrict__ wb,
                                               uint32_t* __restrict__ pk,
                                               float* __restrict__ aggA,
                                               float* __restrict__ aggB) {
  __shared__ __align__(16) unsigned short lds[2 * 16384]; // 64KB: 2 bufs x (A 16KB|B 16KB)
  __shared__ float aggL[128];                             // 64 ch x (A,B)

  const int tid = threadIdx.x;
  const int w = tid >> 6;
  const int lane = tid & 63;
  const int wr = w >> 1;          // A-row half
  const int wc = w & 1;           // channel half (32-ch group)
  // T1 bijective XCD swizzle: 4096 = 512 mblk x 8 nblk
  const int orig = blockIdx.x;
  const int wg = (orig & 7) * 512 + (orig >> 3);
  const int mblk = wg >> 3;
  const int nblk = wg & 7;
  const int m0 = mblk * 128;
  const int n0 = nblk * 64;

  const int lrow = lane >> 3;                    // 0..7
  const int lcol = (((lane & 7) ^ lrow) * 8);    // pre-swizzled source column (bf16)

  // hoisted staging source pointers (advance by kt*64 elems in-loop)
  const unsigned short* pA[4];
  const unsigned short* pB[4];
#pragma unroll
  for (int i = 0; i < 4; ++i) {
    int row = i * 32 + w * 8 + lrow;
    pA[i] = xb + (size_t)(m0 + row) * NK + lcol;
    int e = (row < 64) ? (n0 + row) : (448 + n0 + row);  // hidden | gate W-rows
    pB[i] = wb + (size_t)e * NK + lcol;
  }

  auto stage = [&](int buf, int kt) {
    unsigned short* base = lds + buf * 16384;
    const int ko = kt << 6;
#pragma unroll
    for (int i = 0; i < 4; ++i) {
      __builtin_amdgcn_global_load_lds(
          (const __attribute__((address_space(1))) void*)(pA[i] + ko),
          (__attribute__((address_space(3))) void*)(base + i * 2048 + w * 512),
          16, 0, 0);
      __builtin_amdgcn_global_load_lds(
          (const __attribute__((address_space(1))) void*)(pB[i] + ko),
          (__attribute__((address_space(3))) void*)(base + 8192 + i * 2048 + w * 512),
          16, 0, 0);
    }
  };

  f32x4 acc[4][4];
#pragma unroll
  for (int i = 0; i < 4; ++i)
#pragma unroll
    for (int j = 0; j < 4; ++j) acc[i][j] = (f32x4)0.0f;

  const int fr = lane & 15;
  const int kg = lane >> 4;

  stage(0, 0);
  __syncthreads();

#pragma unroll 1
  for (int kt = 0; kt < 8; ++kt) {
    const int cur = kt & 1;
    if (kt < 7) stage(cur ^ 1, kt + 1);   // issue next-tile loads FIRST

    const char* ldsA = (const char*)(lds + cur * 16384);
    const char* ldsB = ldsA + 16384;
#pragma unroll
    for (int kk = 0; kk < 64; kk += 32) {
      bf16x8 af[4], bfr[4];
#pragma unroll
      for (int i = 0; i < 4; ++i) {
        int rowA = wr * 64 + i * 16 + fr;
        int swzA = (kk * 2 + kg * 16) ^ ((rowA & 7) << 4);
        af[i] = *reinterpret_cast<const bf16x8*>(ldsA + rowA * 128 + swzA);
        // mixed hidden/gate B-frag rows
        int rowB = ((i < 2) ? (wc * 32 + i * 16) : (64 + wc * 32 + (i - 2) * 16)) + fr;
        int swzB = (kk * 2 + kg * 16) ^ ((rowB & 7) << 4);
        bfr[i] = *reinterpret_cast<const bf16x8*>(ldsB + rowB * 128 + swzB);
      }
#pragma unroll
      for (int i = 0; i < 4; ++i)
#pragma unroll
        for (int j = 0; j < 4; ++j)
          acc[i][j] = __builtin_amdgcn_mfma_f32_16x16x32_bf16(af[i], bfr[j], acc[i][j], 0, 0, 0);
    }
    __syncthreads();   // one barrier per K-tile
  }

  // ---------------- epilogue: pure-register a/b + chunk aggregates ----------------
  const float LOG2E = 1.44269504f;
  float A64[2], B64[2];
#pragma unroll
  for (int n = 0; n < 2; ++n) {
    const int ch = wc * 32 + n * 16 + fr;
    float Am[4], Bm[4];
#pragma unroll
    for (int m = 0; m < 4; ++m) {
      float As = 1.0f, Bs = 0.0f;
#pragma unroll
      for (int r = 0; r < 4; ++r) {
        float hid = acc[m][n][r];
        float gat = acc[m][n + 2][r];
        float ex1 = __builtin_amdgcn_exp2f(gat * LOG2E);      // exp(gat)
        float a = __builtin_amdgcn_rcpf(1.0f + ex1);          // sigmoid(-gate)
        float z = 1.0f - a;                                   // sigmoid(gate)
        float ex2 = __builtin_amdgcn_exp2f(-hid * LOG2E);     // exp(-hid)
        float gn = __builtin_amdgcn_rcpf(1.0f + ex2);         // sigmoid(hid)
        float g = (hid >= 0.0f) ? (hid + 0.5f) : gn;
        float bb = z * g;
        int row = 64 * wr + 16 * m + 4 * kg + r;
        pk[(size_t)(m0 + row) * ND + n0 + ch] =
            ((uint32_t)f2bf(bb) << 16) | (uint32_t)f2bf(a);
        Bs = fmaf(a, Bs, bb);   // ordered: r ascending
        As *= a;
      }
      Am[m] = As; Bm[m] = Bs;
    }
    // ordered affine all-reduce across kg (4-row segments within 16-row groups)
#pragma unroll
    for (int m = 0; m < 4; ++m) {
      float pA_ = __shfl_xor(Am[m], 16);
      float pB_ = __shfl_xor(Bm[m], 16);
      Bm[m] = (kg & 1) ? fmaf(Am[m], pB_, Bm[m]) : fmaf(pA_, Bm[m], pB_);
      Am[m] *= pA_;
      pA_ = __shfl_xor(Am[m], 32);
      pB_ = __shfl_xor(Bm[m], 32);
      Bm[m] = (kg & 2) ? fmaf(Am[m], pB_, Bm[m]) : fmaf(pA_, Bm[m], pB_);
      Am[m] *= pA_;
    }
    // serial over 16-row groups (ascending)
    float As = Am[0], Bs = Bm[0];
#pragma unroll
    for (int m = 1; m < 4; ++m) { Bs = fmaf(Am[m], Bs, Bm[m]); As *= Am[m]; }
    A64[n] = As; B64[n] = Bs;
  }
  // cross-wr combine (rows 0-63 then 64-127) via 512B LDS
  if (wr == 0 && kg == 0) {
#pragma unroll
    for (int n = 0; n < 2; ++n) {
      int ch = wc * 32 + n * 16 + fr;
      aggL[ch * 2] = A64[n];
      aggL[ch * 2 + 1] = B64[n];
    }
  }
  __syncthreads();
  if (wr == 1 && kg == 0) {
#pragma unroll
    for (int n = 0; n < 2; ++n) {
      int ch = wc * 32 + n * 16 + fr;
      float A0 = aggL[ch * 2], B0 = aggL[ch * 2 + 1];
      size_t o = (size_t)mblk * ND + n0 + ch;    // mblk == global chunk index
      aggA[o] = A0 * A64[n];
      aggB[o] = fmaf(A64[n], B0, B64[n]);
    }
  }
}

// ---------------- scan pass2: prefix + rescan, write out f32 ----------------
__global__ __launch_bounds__(256) void scan_pass2(const uint32_t* __restrict__ pk,
                                                  const float* __restrict__ aggA,
                                                  const float* __restrict__ aggB,
                                                  float* __restrict__ out,
                                                  float* __restrict__ nextp) {
  int bid = blockIdx.x;
  int b = bid >> 6;
  int c = bid & 63;
  int d2 = threadIdx.x;        // channel-pair 0..255

  float h0 = 0.0f, h1 = 0.0f;
  for (int cc = 0; cc < c; ++cc) {
    int o = (b * 64 + cc) * ND + d2 * 2;
    float2 Aa = *reinterpret_cast<const float2*>(&aggA[o]);
    float2 Bb = *reinterpret_cast<const float2*>(&aggB[o]);
    h0 = fmaf(Aa.x, h0, Bb.x);
    h1 = fmaf(Aa.y, h1, Bb.y);
  }
  size_t base = (size_t)(b * NS + c * 128) * ND + d2 * 2;
#pragma unroll 4
  for (int t = 0; t < 128; ++t) {
    size_t idx = base + (size_t)t * ND;
    uint2 v = *reinterpret_cast<const uint2*>(pk + idx);
    float a0 = __uint_as_float(v.x << 16);
    float b0 = __uint_as_float(v.x & 0xffff0000u);
    float a1 = __uint_as_float(v.y << 16);
    float b1 = __uint_as_float(v.y & 0xffff0000u);
    h0 = fmaf(a0, h0, b0);
    h1 = fmaf(a1, h1, b1);
    *reinterpret_cast<float2*>(&out[idx]) = make_float2(h0, h1);
  }
  if (c == 63) {
    *reinterpret_cast<float2*>(&nextp[b * ND + d2 * 2]) = make_float2(h0, h1);
  }
}

// ---------------- launcher ----------------
extern "C" void kernel_launch(void* const* d_in, const int* in_sizes, int n_in,
                              void* d_out, int out_size, void* d_ws, size_t ws_size,
                              hipStream_t stream) {
  const float* x = (const float*)d_in[0];   // (8, 8192, 512) f32
  const float* W = (const float*)d_in[1];   // (1024, 512) f32
  float* out = (float*)d_out;               // 33554432 + 4096 f32

  char* ws = (char*)d_ws;
  unsigned short* xb  = (unsigned short*)ws;                              // 64 MB
  unsigned short* wbf = (unsigned short*)(ws + (size_t)64 * 1024 * 1024); // 1 MB
  uint32_t* pk = (uint32_t*)(ws + (size_t)65 * 1024 * 1024);              // 128 MB
  float* aggA = (float*)(ws + (size_t)193 * 1024 * 1024);                 // 1 MB
  float* aggB = (float*)(ws + (size_t)194 * 1024 * 1024);                 // 1 MB
  float* nextp = out + (size_t)NM * ND;

  cvt_bf16<<<16384, 256, 0, stream>>>(x, xb, (NM * NK) / 8);
  cvt_bf16<<<256, 256, 0, stream>>>(W, wbf, (1024 * NK) / 8);
  gemm_ab<<<4096, 256, 0, stream>>>(xb, wbf, pk, aggA, aggB);
  scan_pass2<<<512, 256, 0, stream>>>(pk, aggA, aggB, out, nextp);
}

// Round 13
// 230.532 us; speedup vs baseline: 1.2908x; 1.0036x over previous
//
#include <hip/hip_runtime.h>
#include <hip/hip_bf16.h>
#include <stdint.h>

typedef float f32x4 __attribute__((ext_vector_type(4)));
typedef __bf16 bf16x8 __attribute__((ext_vector_type(8)));
typedef unsigned short ushort8 __attribute__((ext_vector_type(8)));

#define NB 8
#define NS 8192
#define ND 512
#define NM (NB * NS)      // 65536 rows
#define NK 512            // reduction dim

// ---------------- helpers ----------------
__device__ __forceinline__ unsigned short f2bf(float f) {
  unsigned u = __float_as_uint(f);
  u += 0x7FFFu + ((u >> 16) & 1u);
  return (unsigned short)(u >> 16);
}

// packed f32x2 -> bf16x2 (RNE)
__device__ __forceinline__ uint32_t cvtpk(float lo, float hi) {
  uint32_t r;
  asm("v_cvt_pk_bf16_f32 %0, %1, %2" : "=v"(r) : "v"(lo), "v"(hi));
  return r;
}

__global__ __launch_bounds__(256) void cvt_bf16(const float* __restrict__ src,
                                                unsigned short* __restrict__ dst,
                                                int n8) {
  int i = blockIdx.x * 256 + threadIdx.x;
  if (i >= n8) return;
  const float4* s = reinterpret_cast<const float4*>(src + (size_t)i * 8);
  float4 v0 = s[0], v1 = s[1];
  ushort8 o;
  o[0] = f2bf(v0.x); o[1] = f2bf(v0.y); o[2] = f2bf(v0.z); o[3] = f2bf(v0.w);
  o[4] = f2bf(v1.x); o[5] = f2bf(v1.y); o[6] = f2bf(v1.z); o[7] = f2bf(v1.w);
  *reinterpret_cast<ushort8*>(dst + (size_t)i * 8) = o;
}

// ---------------- 128x128 GEMM, BK=32, f32-A direct staging (kills cvt_x) ------
// Block: 128 seq rows (= one scan chunk) x 64 channels (128 W-rows: 64 hidden +
// 64 gate, mixed B-frag mapping so hid/gat pair in-thread). 4 waves.
// A staged DIRECTLY from f32 x via global_load_lds (16KB f32/buf); converted to
// bf16 with v_cvt_pk_bf16_f32 at the ds_read->MFMA boundary. B staged bf16 (8KB).
// 2-phase double-buffer, one __syncthreads per K-tile (R11's verified schedule).
// LDS 48KB -> 3 blocks/CU. Swizzles: A chunk c holds global chunk c^(row&7);
// B chunk c holds c^(row&3). T1 XCD grid swizzle.
// Epilogue (identical to R11): in-register a/b, packed pk, fused chunk aggregates.
__global__ __launch_bounds__(256) void gemm_ab(const float* __restrict__ x,
                                               const unsigned short* __restrict__ wb,
                                               uint32_t* __restrict__ pk,
                                               float* __restrict__ aggA,
                                               float* __restrict__ aggB) {
  __shared__ __align__(16) char lds[2 * 24576];   // 48KB: buf{0,1} x (A f32 16KB | B bf16 8KB)
  __shared__ float aggL[128];                     // 64 ch x (A,B)

  const int tid = threadIdx.x;
  const int w = tid >> 6;
  const int lane = tid & 63;
  const int wr = w >> 1;          // A-row half
  const int wc = w & 1;           // channel half (32-ch group)
  // T1 bijective XCD swizzle: 4096 = 512 mblk x 8 nblk
  const int orig = blockIdx.x;
  const int wg = (orig & 7) * 512 + (orig >> 3);
  const int mblk = wg >> 3;
  const int nblk = wg & 7;
  const int m0 = mblk * 128;
  const int n0 = nblk * 64;

  // ---- A staging (f32): 4 loads/thread, slot=(g*4+w)*64+lane, row=slot>>3,
  //      chunk c=lane&7; source chunk = c ^ (row&7), row&7 = lane>>3.
  const int aSrc = (((lane & 7) ^ (lane >> 3)) << 2);   // f32 elems
  const float* pAf[4];
#pragma unroll
  for (int g = 0; g < 4; ++g) {
    int row = g * 32 + w * 8 + (lane >> 3);
    pAf[g] = x + (size_t)(m0 + row) * NK + aSrc;
  }
  // ---- B staging (bf16): 2 loads/thread, slot=(g*4+w)*64+lane, row=slot>>2,
  //      chunk c=lane&3; source chunk = c ^ (row&3), row&3 = (lane>>2)&3.
  const int bSrc = (((lane & 3) ^ ((lane >> 2) & 3)) << 3);  // bf16 elems
  const unsigned short* pBf[2];
#pragma unroll
  for (int g = 0; g < 2; ++g) {
    int row = g * 64 + w * 16 + (lane >> 2);
    int e = (row < 64) ? (n0 + row) : (448 + n0 + row);  // hidden | gate W-rows
    pBf[g] = wb + (size_t)e * NK + bSrc;
  }

  auto stage = [&](int buf, int kt) {
    char* base = lds + buf * 24576;
    const int ko = kt << 5;      // 32 elems (f32 for A, bf16 for B)
#pragma unroll
    for (int g = 0; g < 4; ++g)
      __builtin_amdgcn_global_load_lds(
          (const __attribute__((address_space(1))) void*)(pAf[g] + ko),
          (__attribute__((address_space(3))) void*)(base + (g * 4 + w) * 1024),
          16, 0, 0);
#pragma unroll
    for (int g = 0; g < 2; ++g)
      __builtin_amdgcn_global_load_lds(
          (const __attribute__((address_space(1))) void*)(pBf[g] + ko),
          (__attribute__((address_space(3))) void*)(base + 16384 + (g * 4 + w) * 1024),
          16, 0, 0);
  };

  f32x4 acc[4][4];
#pragma unroll
  for (int i = 0; i < 4; ++i)
#pragma unroll
    for (int j = 0; j < 4; ++j) acc[i][j] = (f32x4)0.0f;

  const int fr = lane & 15;
  const int kg = lane >> 4;

  stage(0, 0);
  __syncthreads();

#pragma unroll 1
  for (int kt = 0; kt < 16; ++kt) {
    const int cur = kt & 1;
    if (kt < 15) stage(cur ^ 1, kt + 1);   // issue next-tile loads FIRST

    const char* ldsA = lds + cur * 24576;
    const char* ldsB = ldsA + 16384;
    bf16x8 af[4], bfr[4];
#pragma unroll
    for (int i = 0; i < 4; ++i) {
      int rowA = wr * 64 + i * 16 + fr;
      int s0 = ((2 * kg) ^ (fr & 7)) << 4;
      int s1 = ((2 * kg + 1) ^ (fr & 7)) << 4;
      f32x4 q0 = *reinterpret_cast<const f32x4*>(ldsA + rowA * 128 + s0);
      f32x4 q1 = *reinterpret_cast<const f32x4*>(ldsA + rowA * 128 + s1);
      uint4 u;
      u.x = cvtpk(q0[0], q0[1]);
      u.y = cvtpk(q0[2], q0[3]);
      u.z = cvtpk(q1[0], q1[1]);
      u.w = cvtpk(q1[2], q1[3]);
      af[i] = *reinterpret_cast<bf16x8*>(&u);
      int rowB = ((i < 2) ? (wc * 32 + i * 16) : (64 + wc * 32 + (i - 2) * 16)) + fr;
      bfr[i] = *reinterpret_cast<const bf16x8*>(ldsB + rowB * 64 + ((kg ^ (fr & 3)) << 4));
    }
#pragma unroll
    for (int i = 0; i < 4; ++i)
#pragma unroll
      for (int j = 0; j < 4; ++j)
        acc[i][j] = __builtin_amdgcn_mfma_f32_16x16x32_bf16(af[i], bfr[j], acc[i][j], 0, 0, 0);

    __syncthreads();   // one barrier per K-tile (drains staged loads, orders buffers)
  }

  // ---------------- epilogue: pure-register a/b + chunk aggregates ----------------
  const float LOG2E = 1.44269504f;
  float A64[2], B64[2];
#pragma unroll
  for (int n = 0; n < 2; ++n) {
    const int ch = wc * 32 + n * 16 + fr;
    float Am[4], Bm[4];
#pragma unroll
    for (int m = 0; m < 4; ++m) {
      float As = 1.0f, Bs = 0.0f;
#pragma unroll
      for (int r = 0; r < 4; ++r) {
        float hid = acc[m][n][r];
        float gat = acc[m][n + 2][r];
        float ex1 = __builtin_amdgcn_exp2f(gat * LOG2E);      // exp(gat)
        float a = __builtin_amdgcn_rcpf(1.0f + ex1);          // sigmoid(-gate)
        float z = 1.0f - a;                                   // sigmoid(gate)
        float ex2 = __builtin_amdgcn_exp2f(-hid * LOG2E);     // exp(-hid)
        float gn = __builtin_amdgcn_rcpf(1.0f + ex2);         // sigmoid(hid)
        float g = (hid >= 0.0f) ? (hid + 0.5f) : gn;
        float bb = z * g;
        int row = 64 * wr + 16 * m + 4 * kg + r;
        pk[(size_t)(m0 + row) * ND + n0 + ch] =
            ((uint32_t)f2bf(bb) << 16) | (uint32_t)f2bf(a);
        Bs = fmaf(a, Bs, bb);   // ordered: r ascending
        As *= a;
      }
      Am[m] = As; Bm[m] = Bs;
    }
    // ordered affine all-reduce across kg (4-row segments within 16-row groups)
#pragma unroll
    for (int m = 0; m < 4; ++m) {
      float pA_ = __shfl_xor(Am[m], 16);
      float pB_ = __shfl_xor(Bm[m], 16);
      Bm[m] = (kg & 1) ? fmaf(Am[m], pB_, Bm[m]) : fmaf(pA_, Bm[m], pB_);
      Am[m] *= pA_;
      pA_ = __shfl_xor(Am[m], 32);
      pB_ = __shfl_xor(Bm[m], 32);
      Bm[m] = (kg & 2) ? fmaf(Am[m], pB_, Bm[m]) : fmaf(pA_, Bm[m], pB_);
      Am[m] *= pA_;
    }
    // serial over 16-row groups (ascending)
    float As = Am[0], Bs = Bm[0];
#pragma unroll
    for (int m = 1; m < 4; ++m) { Bs = fmaf(Am[m], Bs, Bm[m]); As *= Am[m]; }
    A64[n] = As; B64[n] = Bs;
  }
  // cross-wr combine (rows 0-63 then 64-127) via 512B LDS
  if (wr == 0 && kg == 0) {
#pragma unroll
    for (int n = 0; n < 2; ++n) {
      int ch = wc * 32 + n * 16 + fr;
      aggL[ch * 2] = A64[n];
      aggL[ch * 2 + 1] = B64[n];
    }
  }
  __syncthreads();
  if (wr == 1 && kg == 0) {
#pragma unroll
    for (int n = 0; n < 2; ++n) {
      int ch = wc * 32 + n * 16 + fr;
      float A0 = aggL[ch * 2], B0 = aggL[ch * 2 + 1];
      size_t o = (size_t)mblk * ND + n0 + ch;    // mblk == global chunk index
      aggA[o] = A0 * A64[n];
      aggB[o] = fmaf(A64[n], B0, B64[n]);
    }
  }
}

// ---------------- scan pass2: prefix + rescan, write out f32 ----------------
__global__ __launch_bounds__(256) void scan_pass2(const uint32_t* __restrict__ pk,
                                                  const float* __restrict__ aggA,
                                                  const float* __restrict__ aggB,
                                                  float* __restrict__ out,
                                                  float* __restrict__ nextp) {
  int bid = blockIdx.x;
  int b = bid >> 6;
  int c = bid & 63;
  int d2 = threadIdx.x;        // channel-pair 0..255

  float h0 = 0.0f, h1 = 0.0f;
  for (int cc = 0; cc < c; ++cc) {
    int o = (b * 64 + cc) * ND + d2 * 2;
    float2 Aa = *reinterpret_cast<const float2*>(&aggA[o]);
    float2 Bb = *reinterpret_cast<const float2*>(&aggB[o]);
    h0 = fmaf(Aa.x, h0, Bb.x);
    h1 = fmaf(Aa.y, h1, Bb.y);
  }
  size_t base = (size_t)(b * NS + c * 128) * ND + d2 * 2;
#pragma unroll 4
  for (int t = 0; t < 128; ++t) {
    size_t idx = base + (size_t)t * ND;
    uint2 v = *reinterpret_cast<const uint2*>(pk + idx);
    float a0 = __uint_as_float(v.x << 16);
    float b0 = __uint_as_float(v.x & 0xffff0000u);
    float a1 = __uint_as_float(v.y << 16);
    float b1 = __uint_as_float(v.y & 0xffff0000u);
    h0 = fmaf(a0, h0, b0);
    h1 = fmaf(a1, h1, b1);
    *reinterpret_cast<float2*>(&out[idx]) = make_float2(h0, h1);
  }
  if (c == 63) {
    *reinterpret_cast<float2*>(&nextp[b * ND + d2 * 2]) = make_float2(h0, h1);
  }
}

// ---------------- launcher ----------------
extern "C" void kernel_launch(void* const* d_in, const int* in_sizes, int n_in,
                              void* d_out, int out_size, void* d_ws, size_t ws_size,
                              hipStream_t stream) {
  const float* x = (const float*)d_in[0];   // (8, 8192, 512) f32
  const float* W = (const float*)d_in[1];   // (1024, 512) f32
  float* out = (float*)d_out;               // 33554432 + 4096 f32

  char* ws = (char*)d_ws;
  uint32_t* pk = (uint32_t*)ws;                                            // 128 MB
  unsigned short* wbf = (unsigned short*)(ws + (size_t)128 * 1024 * 1024); // 1 MB
  float* aggA = (float*)(ws + (size_t)129 * 1024 * 1024);                  // 1 MB
  float* aggB = (float*)(ws + (size_t)130 * 1024 * 1024);                  // 1 MB
  float* nextp = out + (size_t)NM * ND;

  cvt_bf16<<<256, 256, 0, stream>>>(W, wbf, (1024 * NK) / 8);
  gemm_ab<<<4096, 256, 0, stream>>>(x, wbf, pk, aggA, aggB);
  scan_pass2<<<512, 256, 0, stream>>>(pk, aggA, aggB, out, nextp);
}